// Round 4
// baseline (576.224 us; speedup 1.0000x reference)
//
#include <hip/hip_runtime.h>

// Fully-fused single kernel.
// out_w(x) = sum over 40 canonical eps in {-1,0,1}^4 of  c_{eps,w} * cos(eps.x)
//   c table = (1/8) * sum over pair completions of (V^T D_w V)[m,m']  (V = batch-
//   uniform real variational circuit; diagonal vanishes since V orthogonal).
// Per block: threads 0..15 simulate V's 16 columns into LDS, threads 0..159
// each produce one (term,w) coefficient (single writer, no atomics).
// Per thread: TWO batch elements packed in the v2f lanes -> every vector op
// is a v_pk_*_f32 serving both elements; 4+4 sincos, ~36 packed complex muls,
// 40-term coefficient contraction from LDS.

typedef float v2f __attribute__((ext_vector_type(2)));

struct c2 { v2f r, i; };

__device__ __forceinline__ c2 cmul(c2 a, c2 b) {          // a*b
    return { a.r * b.r - a.i * b.i, a.r * b.i + a.i * b.r };
}
__device__ __forceinline__ c2 cmulc(c2 a, c2 b) {         // a*conj(b)
    return { a.r * b.r + a.i * b.i, a.i * b.r - a.r * b.i };
}

// canonical term codes: base-3 digits d_u = eps_u+1 (wire 0 = msd);
// canonical iff first non-1 digit == 2 (i.e. first nonzero eps is +1).
__device__ __forceinline__ constexpr int firstnz(int t) {
    const int d0 = t / 27, d1 = (t / 9) % 3, d2 = (t / 3) % 3, d3 = t % 3;
    return d0 != 1 ? d0 : d1 != 1 ? d1 : d2 != 1 ? d2 : d3 != 1 ? d3 : 1;
}
__device__ __forceinline__ constexpr int crank(int t) {   // rank among canonical codes
    int r = 0;
    for (int s = 0; s < t; ++s) r += (firstnz(s) == 2);
    return r;
}

__global__ __launch_bounds__(256, 4) void qfused_kernel(
    const float4* __restrict__ in4,     // (B,4) as float4
    const float*  __restrict__ params,  // (2,4), batch-uniform
    float4*       __restrict__ out4,    // (B,4) as float4
    int B2)                             // B/2
{
    __shared__ float  V[16][16];        // V[row][col]
    __shared__ float4 T4[40];           // coefficients per canonical term (x,y,z,w = wires 0..3)
    const int tid = threadIdx.x;

    // ---- phase 1: simulate variational circuit columns ----
    if (tid < 16) {
        float col[16];
        #pragma unroll
        for (int j = 0; j < 16; ++j) col[j] = (j == tid) ? 1.f : 0.f;
        auto cnot = [&](int cm, int tm) {
            #pragma unroll
            for (int j = 0; j < 16; ++j)
                if ((j & cm) && !(j & tm)) { int k = j | tm; float t0 = col[j]; col[j] = col[k]; col[k] = t0; }
        };
        auto ry = [&](int m, float c, float s) {
            #pragma unroll
            for (int j = 0; j < 16; ++j)
                if (!(j & m)) { int k = j | m; float a0 = col[j], a1 = col[k]; col[j] = c*a0 - s*a1; col[k] = s*a0 + c*a1; }
        };
        cnot(8, 4); cnot(4, 2); cnot(2, 1);          // feature-map CNOT chain
        #pragma unroll
        for (int l = 0; l < 2; ++l) {
            float cp[4], sp[4];
            #pragma unroll
            for (int w = 0; w < 4; ++w) __sincosf(0.5f * params[l*4 + w], &sp[w], &cp[w]);
            ry(8, cp[0], sp[0]); ry(4, cp[1], sp[1]); ry(2, cp[2], sp[2]); ry(1, cp[3], sp[3]);
            cnot(8, 4); cnot(4, 2); cnot(2, 1); cnot(1, 8);
        }
        #pragma unroll
        for (int j = 0; j < 16; ++j) V[j][tid] = col[j];
    }
    __syncthreads();

    // ---- phase 2: coefficient table, one thread per (term, wire) ----
    if (tid < 160) {
        const int term = tid >> 2, w = tid & 3;
        int t = 0, cnt = -1;
        for (int s = 0; s < 81; ++s) {                 // term-th canonical code (ascending)
            if (firstnz(s) == 2) { if (++cnt == term) { t = s; break; } }
        }
        int reqm = 0, reqv = 0, pw = 27;
        #pragma unroll
        for (int u = 0; u < 4; ++u) {
            const int d = (t / pw) % 3;
            if (d != 1) { reqm |= 1 << (3 - u); if (d == 2) reqv |= 1 << (3 - u); }
            pw /= 3;
        }
        float g = 0.f;
        for (int m = 0; m < 16; ++m) {
            if ((m & reqm) == reqv) {
                const int mp = m ^ reqm;
                float acc = 0.f;
                #pragma unroll
                for (int k = 0; k < 16; ++k) {
                    const float sg = ((k >> (3 - w)) & 1) ? -1.f : 1.f;
                    acc += sg * V[k][m] * V[k][mp];
                }
                g += acc;
            }
        }
        ((float*)&T4[term])[w] = 0.125f * g;           // 2/16 weight (both pair orders)
    }
    __syncthreads();

    // ---- phase 3: two batch elements per thread ----
    const int gid = blockIdx.x * blockDim.x + tid;
    if (gid >= B2) return;                             // after all barriers

    const float4 xa = in4[2 * gid];
    const float4 xb = in4[2 * gid + 1];

    c2 e0, e1, e2, e3;
    {
        float s0, c0, s1, c1;
        __sincosf(xa.x, &s0, &c0); __sincosf(xb.x, &s1, &c1); e0 = { (v2f){c0, c1}, (v2f){s0, s1} };
        __sincosf(xa.y, &s0, &c0); __sincosf(xb.y, &s1, &c1); e1 = { (v2f){c0, c1}, (v2f){s0, s1} };
        __sincosf(xa.z, &s0, &c0); __sincosf(xb.z, &s1, &c1); e2 = { (v2f){c0, c1}, (v2f){s0, s1} };
        __sincosf(xa.w, &s0, &c0); __sincosf(xb.w, &s1, &c1); e3 = { (v2f){c0, c1}, (v2f){s0, s1} };
    }

    // prefix products over wires 0..2
    const c2 E  = cmul (e0, e1);     // (2,2,.)
    const c2 C  = cmulc(e0, e1);     // (2,0,.)
    const c2 B0 = cmulc(e1, e2);     // (1,2,0)
    const c2 B2v = cmul(e1, e2);     // (1,2,2)
    const c2 C0 = cmulc(C,  e2);     // (2,0,0)
    const c2 C2v = cmul(C,  e2);     // (2,0,2)
    const c2 D0 = cmulc(e0, e2);     // (2,1,0)
    const c2 D2v = cmul(e0, e2);     // (2,1,2)
    const c2 E0 = cmulc(E,  e2);     // (2,2,0)
    const c2 E2v = cmul(E,  e2);     // (2,2,2)

    const v2f c3 = e3.r, s3 = e3.i;
    v2f a0 = (v2f){0.f, 0.f}, a1 = a0, a2 = a0, a3 = a0;

    auto ACC = [&](int t, v2f cv) {
        const float4 cf = T4[crank(t)];                // uniform LDS addr -> broadcast
        a0 += cv * cf.x; a1 += cv * cf.y; a2 += cv * cf.z; a3 += cv * cf.w;
    };
    // prefix (1,1,1): only d3=+1 is canonical -> cv = Re(e3)
    ACC(41, c3);
    // all other prefixes contribute d3 = -1, 0, +1 (t+0, t+1, t+2)
    auto TRI = [&](int tb, c2 P) {
        const v2f u = P.r * c3, v = P.i * s3;
        ACC(tb + 1, P.r);          // d3 = 0
        ACC(tb + 2, u - v);        // d3 = +1 : Re(P*e3)
        ACC(tb + 0, u + v);        // d3 = -1 : Re(P*conj(e3))
    };
    TRI(42, e2);  TRI(45, B0); TRI(48, e1); TRI(51, B2v);
    TRI(54, C0);  TRI(57, C);  TRI(60, C2v);
    TRI(63, D0);  TRI(66, e0); TRI(69, D2v);
    TRI(72, E0);  TRI(75, E);  TRI(78, E2v);

    out4[2 * gid]     = make_float4(a0.x, a1.x, a2.x, a3.x);
    out4[2 * gid + 1] = make_float4(a0.y, a1.y, a2.y, a3.y);
}

extern "C" void kernel_launch(void* const* d_in, const int* in_sizes, int n_in,
                              void* d_out, int out_size, void* d_ws, size_t ws_size,
                              hipStream_t stream) {
    const float4* in4   = (const float4*)d_in[0];
    const float*  params = (const float*)d_in[1];
    float4* out4 = (float4*)d_out;
    const int B  = in_sizes[0] / 4;
    const int B2 = B / 2;                       // B = 1048576, exact
    const int threads = 256;
    const int blocks = (B2 + threads - 1) / threads;
    qfused_kernel<<<blocks, threads, 0, stream>>>(in4, params, out4, B2);
}

// Round 5
// 77.793 us; speedup vs baseline: 7.4072x; 7.4072x over previous
//
#include <hip/hip_runtime.h>

// Fully-fused single kernel.
// out_w(x) = sum over 40 canonical eps in {-1,0,1}^4 of  c_{eps,w} * cos(eps.x)
//   c table = (1/8) * sum over pair completions of (V^T D_w V)[m,m']  (V = batch-
//   uniform real variational circuit; diagonal vanishes since V orthogonal).
// Canonical term codes (base-3 digits d_u = eps_u+1, wire 0 = msd, first non-1
// digit == 2) are EXACTLY t in [41,80] -> table index = t-41, no rank search.
// Per block: threads 0..15 simulate V's 16 columns into LDS, threads 0..159
// each produce one (term,w) coefficient (single writer, no atomics).
// Per thread: TWO batch elements packed in v2f lanes (v_pk_*_f32).
// NOTE: no min-waves launch_bounds hint — R4's (256,4) capped VGPRs at 64 and
// spilled ~200 B/thread to scratch (WRITE_SIZE 121 MB, 521 us).

typedef float v2f __attribute__((ext_vector_type(2)));

struct c2 { v2f r, i; };

__device__ __forceinline__ c2 cmul(c2 a, c2 b) {          // a*b
    return { a.r * b.r - a.i * b.i, a.r * b.i + a.i * b.r };
}
__device__ __forceinline__ c2 cmulc(c2 a, c2 b) {         // a*conj(b)
    return { a.r * b.r + a.i * b.i, a.i * b.r - a.r * b.i };
}

__global__ __launch_bounds__(256) void qfused_kernel(
    const float4* __restrict__ in4,     // (B,4) as float4
    const float*  __restrict__ params,  // (2,4), batch-uniform
    float4*       __restrict__ out4,    // (B,4) as float4
    int B2)                             // B/2
{
    __shared__ float  V[16][16];        // V[row][col]
    __shared__ float4 T4[40];           // coeffs per canonical term (x..w = wires 0..3)
    const int tid = threadIdx.x;

    // ---- phase 1: simulate variational circuit columns ----
    if (tid < 16) {
        float col[16];
        #pragma unroll
        for (int j = 0; j < 16; ++j) col[j] = (j == tid) ? 1.f : 0.f;
        auto cnot = [&](int cm, int tm) {
            #pragma unroll
            for (int j = 0; j < 16; ++j)
                if ((j & cm) && !(j & tm)) { int k = j | tm; float t0 = col[j]; col[j] = col[k]; col[k] = t0; }
        };
        auto ry = [&](int m, float c, float s) {
            #pragma unroll
            for (int j = 0; j < 16; ++j)
                if (!(j & m)) { int k = j | m; float a0 = col[j], a1 = col[k]; col[j] = c*a0 - s*a1; col[k] = s*a0 + c*a1; }
        };
        cnot(8, 4); cnot(4, 2); cnot(2, 1);          // feature-map CNOT chain
        #pragma unroll
        for (int l = 0; l < 2; ++l) {
            float cp[4], sp[4];
            #pragma unroll
            for (int w = 0; w < 4; ++w) __sincosf(0.5f * params[l*4 + w], &sp[w], &cp[w]);
            ry(8, cp[0], sp[0]); ry(4, cp[1], sp[1]); ry(2, cp[2], sp[2]); ry(1, cp[3], sp[3]);
            cnot(8, 4); cnot(4, 2); cnot(2, 1); cnot(1, 8);
        }
        #pragma unroll
        for (int j = 0; j < 16; ++j) V[j][tid] = col[j];
    }
    __syncthreads();

    // ---- phase 2: coefficient table, one thread per (term, wire) ----
    if (tid < 160) {
        const int term = tid >> 2, w = tid & 3;
        const int t = 41 + term;                       // canonical codes are [41,80]
        int reqm = 0, reqv = 0, pw = 27;
        #pragma unroll
        for (int u = 0; u < 4; ++u) {
            const int d = (t / pw) % 3;
            if (d != 1) { reqm |= 1 << (3 - u); if (d == 2) reqv |= 1 << (3 - u); }
            pw /= 3;
        }
        float g = 0.f;
        for (int m = 0; m < 16; ++m) {
            if ((m & reqm) == reqv) {
                const int mp = m ^ reqm;
                float acc = 0.f;
                #pragma unroll
                for (int k = 0; k < 16; ++k) {
                    const float sg = ((k >> (3 - w)) & 1) ? -1.f : 1.f;
                    acc += sg * V[k][m] * V[k][mp];
                }
                g += acc;
            }
        }
        ((float*)&T4[term])[w] = 0.125f * g;           // 2/16 weight (both pair orders)
    }
    __syncthreads();

    // ---- phase 3: two batch elements per thread ----
    const int gid = blockIdx.x * blockDim.x + tid;
    if (gid >= B2) return;                             // after all barriers

    const float4 xa = in4[2 * gid];
    const float4 xb = in4[2 * gid + 1];

    c2 e0, e1, e2, e3;
    {
        float s0, c0, s1, c1;
        __sincosf(xa.x, &s0, &c0); __sincosf(xb.x, &s1, &c1); e0 = { (v2f){c0, c1}, (v2f){s0, s1} };
        __sincosf(xa.y, &s0, &c0); __sincosf(xb.y, &s1, &c1); e1 = { (v2f){c0, c1}, (v2f){s0, s1} };
        __sincosf(xa.z, &s0, &c0); __sincosf(xb.z, &s1, &c1); e2 = { (v2f){c0, c1}, (v2f){s0, s1} };
        __sincosf(xa.w, &s0, &c0); __sincosf(xb.w, &s1, &c1); e3 = { (v2f){c0, c1}, (v2f){s0, s1} };
    }

    const v2f c3 = e3.r, s3 = e3.i;
    v2f a0 = (v2f){0.f, 0.f}, a1 = a0, a2 = a0, a3 = a0;

    auto ACC = [&](int idx, v2f cv) {                  // idx = t-41, compile-time const
        const float4 cf = T4[idx];                     // uniform LDS addr -> broadcast
        a0 += cv * cf.x; a1 += cv * cf.y; a2 += cv * cf.z; a3 += cv * cf.w;
    };
    auto TRI = [&](int rb, c2 P) {                     // ranks rb+0/1/2 = d3 0/1/2
        const v2f u = P.r * c3, v = P.i * s3;
        ACC(rb + 1, P.r);          // eps3 =  0
        ACC(rb + 2, u - v);        // eps3 = +1 : Re(P*e3)
        ACC(rb + 0, u + v);        // eps3 = -1 : Re(P*conj(e3))
    };

    ACC(0, c3);                    // prefix (1,1,1), only eps3=+1 canonical
    TRI(1,  e2);                   // (1,1,2,.)
    TRI(4,  cmulc(e1, e2));        // (1,2,0,.)
    TRI(7,  e1);                   // (1,2,1,.)
    TRI(10, cmul (e1, e2));        // (1,2,2,.)
    const c2 C = cmulc(e0, e1);
    TRI(13, cmulc(C, e2));         // (2,0,0,.)
    TRI(16, C);                    // (2,0,1,.)
    TRI(19, cmul (C, e2));         // (2,0,2,.)
    TRI(22, cmulc(e0, e2));        // (2,1,0,.)
    TRI(25, e0);                   // (2,1,1,.)
    TRI(28, cmul (e0, e2));        // (2,1,2,.)
    const c2 E = cmul(e0, e1);
    TRI(31, cmulc(E, e2));         // (2,2,0,.)
    TRI(34, E);                    // (2,2,1,.)
    TRI(37, cmul (E, e2));         // (2,2,2,.)

    out4[2 * gid]     = make_float4(a0.x, a1.x, a2.x, a3.x);
    out4[2 * gid + 1] = make_float4(a0.y, a1.y, a2.y, a3.y);
}

extern "C" void kernel_launch(void* const* d_in, const int* in_sizes, int n_in,
                              void* d_out, int out_size, void* d_ws, size_t ws_size,
                              hipStream_t stream) {
    const float4* in4    = (const float4*)d_in[0];
    const float*  params = (const float*)d_in[1];
    float4* out4 = (float4*)d_out;
    const int B  = in_sizes[0] / 4;
    const int B2 = B / 2;                       // B = 1048576, exact
    const int threads = 256;
    const int blocks = (B2 + threads - 1) / threads;
    qfused_kernel<<<blocks, threads, 0, stream>>>(in4, params, out4, B2);
}